// Round 1
// baseline (5649.966 us; speedup 1.0000x reference)
//
#include <hip/hip_runtime.h>

// Problem constants
#define BATCH   2
#define SEQ     2048
#define DMODEL  1024
#define DINNER  2048
#define NHEADS  32
#define HEADDIM 64
#define DSTATE  128
#define BLTOT   (BATCH * SEQ)          // 4096 rows

// Workspace layout (float offsets)
#define OFF_X     0                    // (BLTOT, DINNER) silu(x)        8388608
#define OFF_SZ    8388608              // (BLTOT, DINNER) silu(z)        8388608
#define OFF_BC    16777216             // (BLTOT, H, 512) BC raw/normed; reused as y  67108864
#define OFF_DT    83886080             // (BLTOT, H)                      131072
#define OFF_XSUM  84017152             // (BLTOT, H)                      131072
#define OFF_YREDP 84148224             // (BLTOT, H, 2) wave partials     262144
// total = 84410368 floats = 337.6 MB

__device__ __forceinline__ float silu_f(float v) {
    return v / (1.0f + __expf(-v));
}
__device__ __forceinline__ float softplus_f(float v) {
    return (v > 20.0f) ? v : log1pf(__expf(v));
}

// ---------------------------------------------------------------------------
// GEMM 1: xz = u @ in_proj_w^T ; fused silu; split into x / silu(z)
// M=4096, N=4096, K=1024.  128x128 tile, 256 thr, 8x8 per thread, BK=16.
// ---------------------------------------------------------------------------
__global__ __launch_bounds__(256) void gemm_xz_kernel(
    const float* __restrict__ Amat, const float* __restrict__ Bmat,
    float* __restrict__ xo, float* __restrict__ szo) {
    const int K = 1024;
    __shared__ float As[16][132];
    __shared__ float Bs[16][132];
    int tid = threadIdx.x;
    int tx = tid & 15, ty = tid >> 4;
    int row0 = blockIdx.y * 128, col0 = blockIdx.x * 128;
    float acc[8][8];
#pragma unroll
    for (int i = 0; i < 8; ++i)
#pragma unroll
        for (int j = 0; j < 8; ++j) acc[i][j] = 0.0f;

    int lk = (tid & 3) << 2;   // 0,4,8,12
    int lr = tid >> 2;         // 0..63

    for (int k0 = 0; k0 < K; k0 += 16) {
#pragma unroll
        for (int rr = 0; rr < 128; rr += 64) {
            float4 av = *(const float4*)&Amat[(row0 + lr + rr) * K + k0 + lk];
            As[lk + 0][lr + rr] = av.x; As[lk + 1][lr + rr] = av.y;
            As[lk + 2][lr + rr] = av.z; As[lk + 3][lr + rr] = av.w;
            float4 bv = *(const float4*)&Bmat[(col0 + lr + rr) * K + k0 + lk];
            Bs[lk + 0][lr + rr] = bv.x; Bs[lk + 1][lr + rr] = bv.y;
            Bs[lk + 2][lr + rr] = bv.z; Bs[lk + 3][lr + rr] = bv.w;
        }
        __syncthreads();
#pragma unroll
        for (int kk = 0; kk < 16; ++kk) {
            float4 a0 = *(const float4*)&As[kk][ty * 8];
            float4 a1 = *(const float4*)&As[kk][ty * 8 + 4];
            float4 b0 = *(const float4*)&Bs[kk][tx * 8];
            float4 b1 = *(const float4*)&Bs[kk][tx * 8 + 4];
            float a[8] = {a0.x, a0.y, a0.z, a0.w, a1.x, a1.y, a1.z, a1.w};
            float b[8] = {b0.x, b0.y, b0.z, b0.w, b1.x, b1.y, b1.z, b1.w};
#pragma unroll
            for (int i = 0; i < 8; ++i)
#pragma unroll
                for (int j = 0; j < 8; ++j) acc[i][j] += a[i] * b[j];
        }
        __syncthreads();
    }

#pragma unroll
    for (int i = 0; i < 8; ++i) {
        int row = row0 + ty * 8 + i;
#pragma unroll
        for (int j = 0; j < 8; ++j) {
            int col = col0 + tx * 8 + j;
            float s = silu_f(acc[i][j]);
            if (col < DINNER) xo[row * DINNER + col] = s;
            else              szo[row * DINNER + (col - DINNER)] = s;
        }
    }
}

// ---------------------------------------------------------------------------
// Kernel 2: dt = softplus(x @ dtw^T + bias), xsum = per-head sum of x.
// One block (256 thr) per (b,l) row; 8 threads per head.
// ---------------------------------------------------------------------------
__global__ __launch_bounds__(256) void dt_xsum_kernel(
    const float* __restrict__ x, const float* __restrict__ dtw,
    const float* __restrict__ dtb, float* __restrict__ dt,
    float* __restrict__ xsum) {
    __shared__ float xs[DINNER];
    int bl = blockIdx.x;
    const float* xr = x + bl * DINNER;
    for (int i = threadIdx.x; i < DINNER; i += 256) xs[i] = xr[i];
    __syncthreads();

    int h = threadIdx.x >> 3, s = threadIdx.x & 7;
    float xa = 0.0f;
#pragma unroll
    for (int j = s; j < HEADDIM; j += 8) xa += xs[h * HEADDIM + j];

    float acc = 0.0f;
    const float* w = dtw + h * DINNER;
    for (int i = s; i < DINNER; i += 8) acc += xs[i] * w[i];

#pragma unroll
    for (int off = 1; off < 8; off <<= 1) {
        acc += __shfl_xor(acc, off);
        xa  += __shfl_xor(xa, off);
    }
    if (s == 0) {
        dt[bl * NHEADS + h]   = softplus_f(acc + dtb[h]);
        xsum[bl * NHEADS + h] = xa;
    }
}

// ---------------------------------------------------------------------------
// GEMM 3: bc = x @ xpw_sel^T.  M=4096, N=16384 (h,cb,n,p), K=2048.
// Weight row for output col c: (c/512)*513 + (c%512)  (drops unused 513th).
// ---------------------------------------------------------------------------
__global__ __launch_bounds__(256) void gemm_bc_kernel(
    const float* __restrict__ Amat, const float* __restrict__ Bmat,
    float* __restrict__ bco) {
    const int K = 2048;
    __shared__ float As[16][132];
    __shared__ float Bs[16][132];
    int tid = threadIdx.x;
    int tx = tid & 15, ty = tid >> 4;
    int row0 = blockIdx.y * 128, col0 = blockIdx.x * 128;
    float acc[8][8];
#pragma unroll
    for (int i = 0; i < 8; ++i)
#pragma unroll
        for (int j = 0; j < 8; ++j) acc[i][j] = 0.0f;

    int lk = (tid & 3) << 2;
    int lr = tid >> 2;

    for (int k0 = 0; k0 < K; k0 += 16) {
#pragma unroll
        for (int rr = 0; rr < 128; rr += 64) {
            float4 av = *(const float4*)&Amat[(row0 + lr + rr) * K + k0 + lk];
            As[lk + 0][lr + rr] = av.x; As[lk + 1][lr + rr] = av.y;
            As[lk + 2][lr + rr] = av.z; As[lk + 3][lr + rr] = av.w;
            int c = col0 + lr + rr;
            int wrow = (c >> 9) * 513 + (c & 511);
            float4 bv = *(const float4*)&Bmat[wrow * K + k0 + lk];
            Bs[lk + 0][lr + rr] = bv.x; Bs[lk + 1][lr + rr] = bv.y;
            Bs[lk + 2][lr + rr] = bv.z; Bs[lk + 3][lr + rr] = bv.w;
        }
        __syncthreads();
#pragma unroll
        for (int kk = 0; kk < 16; ++kk) {
            float4 a0 = *(const float4*)&As[kk][ty * 8];
            float4 a1 = *(const float4*)&As[kk][ty * 8 + 4];
            float4 b0 = *(const float4*)&Bs[kk][tx * 8];
            float4 b1 = *(const float4*)&Bs[kk][tx * 8 + 4];
            float a[8] = {a0.x, a0.y, a0.z, a0.w, a1.x, a1.y, a1.z, a1.w};
            float b[8] = {b0.x, b0.y, b0.z, b0.w, b1.x, b1.y, b1.z, b1.w};
#pragma unroll
            for (int i = 0; i < 8; ++i)
#pragma unroll
                for (int j = 0; j < 8; ++j) acc[i][j] += a[i] * b[j];
        }
        __syncthreads();
    }

#pragma unroll
    for (int i = 0; i < 8; ++i) {
        int row = row0 + ty * 8 + i;
#pragma unroll
        for (int j = 0; j < 8; ++j) {
            int col = col0 + tx * 8 + j;
            bco[row * 16384 + col] = acc[i][j];
        }
    }
}

// ---------------------------------------------------------------------------
// Kernel 4: in-place RMS norm over 256-element groups (B and C per head).
// One wave (64 thr) per group; group id g = bl*64 + h*2 + cb.
// ---------------------------------------------------------------------------
__global__ __launch_bounds__(64) void rmsnorm_kernel(
    float* __restrict__ bc, const float* __restrict__ wB,
    const float* __restrict__ wC) {
    int g = blockIdx.x;
    int cb = g & 1;
    float* p = bc + (size_t)g * 256;
    int t = threadIdx.x;
    float4 v = *(float4*)&p[t * 4];
    float ss = v.x * v.x + v.y * v.y + v.z * v.z + v.w * v.w;
#pragma unroll
    for (int off = 1; off < 64; off <<= 1) ss += __shfl_xor(ss, off);
    float scale = rsqrtf(ss * (1.0f / 256.0f) + 1e-6f);
    const float* w = cb ? wC : wB;
    float4 wv = *(const float4*)&w[t * 4];
    v.x *= scale * wv.x; v.y *= scale * wv.y;
    v.z *= scale * wv.z; v.w *= scale * wv.w;
    *(float4*)&p[t * 4] = v;
}

// ---------------------------------------------------------------------------
// Kernel 5: complex bilinear scan. One block per (b,h), 128 threads = states.
// Writes per-wave y partials (no intra-block barrier needed).
// ---------------------------------------------------------------------------
__global__ __launch_bounds__(128) void scan_kernel(
    const float* __restrict__ bc, const float* __restrict__ dt,
    const float* __restrict__ xsum, const float* __restrict__ A,
    float* __restrict__ yredp) {
    int bh = blockIdx.x;          // b*32 + h
    int b = bh >> 5, h = bh & 31;
    int n = threadIdx.x;          // state index 0..127
    float ar = A[(h * DSTATE + n) * 2 + 0];
    float ai = A[(h * DSTATE + n) * 2 + 1];
    float hr = 0.0f, hi = 0.0f;

    const float* base = bc + (size_t)b * SEQ * 16384 + h * 512;
    const float* dtp  = dt + b * SEQ * NHEADS + h;
    const float* xsp  = xsum + b * SEQ * NHEADS + h;
    int wv = n >> 6, lane = n & 63;
    float* yp = yredp + ((size_t)(b * SEQ) * NHEADS + h) * 2 + wv;

    float2 Bv = *(const float2*)&base[n * 2];
    float2 Cv = *(const float2*)&base[256 + n * 2];
    float dtv = dtp[0], xsv = xsp[0];

    for (int l = 0; l < SEQ; ++l) {
        float2 Bn = {0.f, 0.f}, Cn = {0.f, 0.f};
        float dtn = 0.f, xsn = 0.f;
        if (l + 1 < SEQ) {
            const float* nb = base + (size_t)(l + 1) * 16384;
            Bn  = *(const float2*)&nb[n * 2];
            Cn  = *(const float2*)&nb[256 + n * 2];
            dtn = dtp[(l + 1) * NHEADS];
            xsn = xsp[(l + 1) * NHEADS];
        }
        // zt = Ac * dt/2; den = 1 - zt; inv = 1/den
        float hd = 0.5f * dtv;
        float ztr = ar * hd, zti = ai * hd;
        float denr = 1.0f - ztr, deni = -zti;
        float s2 = 1.0f / (denr * denr + deni * deni);
        float invr = denr * s2, invi = zti * s2;   // conj(den)*s2
        float opr = 1.0f + ztr;
        float abr = opr * invr - zti * invi;
        float abi = opr * invi + zti * invr;
        float coef = dtv * xsv;
        float cr = coef * invr, ci = coef * invi;
        float ur = Bv.x * cr - Bv.y * ci;
        float ui = Bv.x * ci + Bv.y * cr;
        float nhr = abr * hr - abi * hi + ur;
        float nhi = abr * hi + abi * hr + ui;
        hr = nhr; hi = nhi;
        float y = Cv.x * hr - Cv.y * hi;
#pragma unroll
        for (int off = 1; off < 64; off <<= 1) y += __shfl_xor(y, off);
        if (lane == 0) yp[(size_t)l * (NHEADS * 2)] = y;
        Bv = Bn; Cv = Cn; dtv = dtn; xsv = xsn;
    }
}

// ---------------------------------------------------------------------------
// Kernel 6: y = x * (yred0 + yred1 + D[h]) * silu(z), elementwise, float4.
// ---------------------------------------------------------------------------
__global__ __launch_bounds__(256) void yfuse_kernel(
    const float* __restrict__ x, const float* __restrict__ sz,
    const float* __restrict__ yredp, const float* __restrict__ Dv,
    float* __restrict__ y) {
    int i = (blockIdx.x * 256 + threadIdx.x) * 4;
    int r = i >> 11;          // / DINNER
    int k = i & (DINNER - 1);
    int h = k >> 6;           // / HEADDIM
    float yr = yredp[(r * NHEADS + h) * 2 + 0] +
               yredp[(r * NHEADS + h) * 2 + 1] + Dv[h];
    float4 xv = *(const float4*)&x[i];
    float4 zv = *(const float4*)&sz[i];
    float4 o;
    o.x = xv.x * yr * zv.x; o.y = xv.y * yr * zv.y;
    o.z = xv.z * yr * zv.z; o.w = xv.w * yr * zv.w;
    *(float4*)&y[i] = o;
}

// ---------------------------------------------------------------------------
// GEMM 7: out = y @ out_proj_w^T.  M=4096, N=1024, K=2048.
// ---------------------------------------------------------------------------
__global__ __launch_bounds__(256) void gemm_out_kernel(
    const float* __restrict__ Amat, const float* __restrict__ Bmat,
    float* __restrict__ out) {
    const int K = 2048;
    __shared__ float As[16][132];
    __shared__ float Bs[16][132];
    int tid = threadIdx.x;
    int tx = tid & 15, ty = tid >> 4;
    int row0 = blockIdx.y * 128, col0 = blockIdx.x * 128;
    float acc[8][8];
#pragma unroll
    for (int i = 0; i < 8; ++i)
#pragma unroll
        for (int j = 0; j < 8; ++j) acc[i][j] = 0.0f;

    int lk = (tid & 3) << 2;
    int lr = tid >> 2;

    for (int k0 = 0; k0 < K; k0 += 16) {
#pragma unroll
        for (int rr = 0; rr < 128; rr += 64) {
            float4 av = *(const float4*)&Amat[(row0 + lr + rr) * K + k0 + lk];
            As[lk + 0][lr + rr] = av.x; As[lk + 1][lr + rr] = av.y;
            As[lk + 2][lr + rr] = av.z; As[lk + 3][lr + rr] = av.w;
            float4 bv = *(const float4*)&Bmat[(col0 + lr + rr) * K + k0 + lk];
            Bs[lk + 0][lr + rr] = bv.x; Bs[lk + 1][lr + rr] = bv.y;
            Bs[lk + 2][lr + rr] = bv.z; Bs[lk + 3][lr + rr] = bv.w;
        }
        __syncthreads();
#pragma unroll
        for (int kk = 0; kk < 16; ++kk) {
            float4 a0 = *(const float4*)&As[kk][ty * 8];
            float4 a1 = *(const float4*)&As[kk][ty * 8 + 4];
            float4 b0 = *(const float4*)&Bs[kk][tx * 8];
            float4 b1 = *(const float4*)&Bs[kk][tx * 8 + 4];
            float a[8] = {a0.x, a0.y, a0.z, a0.w, a1.x, a1.y, a1.z, a1.w};
            float b[8] = {b0.x, b0.y, b0.z, b0.w, b1.x, b1.y, b1.z, b1.w};
#pragma unroll
            for (int i = 0; i < 8; ++i)
#pragma unroll
                for (int j = 0; j < 8; ++j) acc[i][j] += a[i] * b[j];
        }
        __syncthreads();
    }

#pragma unroll
    for (int i = 0; i < 8; ++i) {
        int row = row0 + ty * 8 + i;
#pragma unroll
        for (int j = 0; j < 8; ++j) {
            int col = col0 + tx * 8 + j;
            out[row * DMODEL + col] = acc[i][j];
        }
    }
}

extern "C" void kernel_launch(void* const* d_in, const int* in_sizes, int n_in,
                              void* d_out, int out_size, void* d_ws, size_t ws_size,
                              hipStream_t stream) {
    const float* u          = (const float*)d_in[0];
    const float* in_proj_w  = (const float*)d_in[1];
    const float* dtw        = (const float*)d_in[2];
    const float* dtb        = (const float*)d_in[3];
    const float* xpw        = (const float*)d_in[4];
    const float* A          = (const float*)d_in[5];
    const float* Dv         = (const float*)d_in[6];
    const float* wB         = (const float*)d_in[7];
    const float* wC         = (const float*)d_in[8];
    const float* opw        = (const float*)d_in[9];
    float* out = (float*)d_out;
    float* ws  = (float*)d_ws;

    float* x     = ws + OFF_X;
    float* sz    = ws + OFF_SZ;
    float* bc    = ws + OFF_BC;
    float* dt    = ws + OFF_DT;
    float* xsum  = ws + OFF_XSUM;
    float* yredp = ws + OFF_YREDP;

    gemm_xz_kernel<<<dim3(32, 32), 256, 0, stream>>>(u, in_proj_w, x, sz);
    dt_xsum_kernel<<<BLTOT, 256, 0, stream>>>(x, dtw, dtb, dt, xsum);
    gemm_bc_kernel<<<dim3(128, 32), 256, 0, stream>>>(x, xpw, bc);
    rmsnorm_kernel<<<BLTOT * NHEADS * 2, 64, 0, stream>>>(bc, wB, wC);
    scan_kernel<<<BATCH * NHEADS, 128, 0, stream>>>(bc, dt, xsum, A, yredp);
    float* y = bc;  // reuse BC buffer (scan has fully consumed it)
    yfuse_kernel<<<BLTOT * DINNER / 4 / 256, 256, 0, stream>>>(x, sz, yredp, Dv, y);
    gemm_out_kernel<<<dim3(8, 32), 256, 0, stream>>>(y, opw, out);
}

// Round 2
// 1892.941 us; speedup vs baseline: 2.9848x; 2.9848x over previous
//
#include <hip/hip_runtime.h>

#define BATCH   2
#define SEQ     2048
#define DMODEL  1024
#define DINNER  2048
#define NHEADS  32
#define HEADDIM 64
#define DSTATE  128
#define BLTOT   (BATCH * SEQ)          // 4096 rows

// ---- workspace layout (byte offsets) --------------------------------------
#define OFF_UB   0ull                  // u bf16        4096x1024   8,388,608
#define OFF_WXZ  8388608ull            // in_proj bf16  4096x1024   8,388,608
#define OFF_WBC  16777216ull           // xpw packed    16384x2048 67,108,864
#define OFF_WOUT 83886080ull           // out_proj bf16 1024x2048   4,194,304
#define OFF_XB   88080384ull           // x bf16        4096x2048  16,777,216
#define OFF_YB   104857600ull          // y bf16        4096x2048  16,777,216
#define OFF_BC   121634816ull          // bc bf16       4096x16384 134,217,728
#define OFF_SZ   255852544ull          // silu(z) f32   4096x2048  33,554,432
#define OFF_DT   289406976ull          // dt f32        4096x32       524,288
#define OFF_XS   289931264ull          // xsum f32      4096x32       524,288
#define OFF_YR   290455552ull          // yred partials 4096x32x2   1,048,576
// total 291,504,128 B = 278 MB (round-0 used 337 MB, so ws_size is enough)

typedef __attribute__((ext_vector_type(8))) short bf16x8;
typedef __attribute__((ext_vector_type(4))) float f32x4;

__device__ __forceinline__ float b2f(unsigned short u) {
    return __uint_as_float(((unsigned)u) << 16);
}
__device__ __forceinline__ unsigned short f2b(float f) {
    unsigned x = __float_as_uint(f);
    unsigned r = (x + 0x7fffu + ((x >> 16) & 1u)) >> 16;   // RNE
    return (unsigned short)r;
}
__device__ __forceinline__ float silu_f(float v) {
    return v / (1.0f + __expf(-v));
}
__device__ __forceinline__ float softplus_f(float v) {
    return (v > 20.0f) ? v : log1pf(__expf(v));
}

__device__ __forceinline__ void gload_lds16(const void* g, void* l) {
    __builtin_amdgcn_global_load_lds(
        (const __attribute__((address_space(1))) unsigned int*)g,
        (__attribute__((address_space(3))) unsigned int*)l, 16, 0, 0);
}

// ---------------------------------------------------------------------------
// fp32 -> bf16 conversion (n divisible by 1024)
// ---------------------------------------------------------------------------
__global__ __launch_bounds__(256) void f2b_kernel(
    const float* __restrict__ in, unsigned short* __restrict__ out) {
    int i = (blockIdx.x * 256 + threadIdx.x) * 4;
    float4 v = *(const float4*)&in[i];
    ushort4 o = {f2b(v.x), f2b(v.y), f2b(v.z), f2b(v.w)};
    *(ushort4*)&out[i] = o;
}

// xpw: (16416, 2048) fp32 -> packed (16384, 2048) bf16, dropping per-head
// row 512 (the dt column duplicate slot). out col c <- src row (c/512)*513+(c%512)
__global__ __launch_bounds__(256) void pack_xpw_kernel(
    const float* __restrict__ in, unsigned short* __restrict__ out) {
    int idx = blockIdx.x * 256 + threadIdx.x;
    int i = idx * 4;
    int c = i >> 11;            // packed row (output column of gemm_bc)
    int k = i & 2047;
    const float* src = in + ((size_t)(c >> 9) * 513 + (c & 511)) * 2048 + k;
    float4 v = *(const float4*)src;
    ushort4 o = {f2b(v.x), f2b(v.y), f2b(v.z), f2b(v.w)};
    *(ushort4*)&out[i] = o;
}

// ---------------------------------------------------------------------------
// MFMA GEMM (m97 structure): C[M,N] = A[M,K] @ B[N,K]^T, bf16 in, fp32 acc.
// 128x128 tile, BK=32, 256 thr = 4 waves, each wave 64x64 via 4x4 16x16x32.
// MODE 0: store fp32 C0 (ld=N).  MODE 1: silu split (x bf16 / sz f32).
// MODE 2: store bf16 C0 (ld=N).
// ---------------------------------------------------------------------------
template <int K, int MODE>
__global__ __launch_bounds__(256) void gemm_mfma(
    const unsigned short* __restrict__ A, const unsigned short* __restrict__ B,
    void* __restrict__ C0, void* __restrict__ C1, int N) {
    __shared__ short ldsA[128 * 32];
    __shared__ short ldsB[128 * 32];
    int tid = threadIdx.x;
    int row0 = blockIdx.y * 128, col0 = blockIdx.x * 128;
    int lane = tid & 63, wave = tid >> 6;
    int wrow = (wave >> 1) * 64, wcol = (wave & 1) * 64;
    int m = lane & 15, quad = lane >> 4;

    f32x4 acc[4][4];
#pragma unroll
    for (int i = 0; i < 4; ++i)
#pragma unroll
        for (int j = 0; j < 4; ++j) acc[i][j] = (f32x4){0.f, 0.f, 0.f, 0.f};

    // staging: thread tid loads 8 bf16 (16B); rows r and r+64
    int r = tid >> 2, c8 = (tid & 3) * 8;
    const unsigned short* Ag = A + (size_t)(row0 + r) * K + c8;
    const unsigned short* Bg = B + (size_t)(col0 + r) * K + c8;
    short* la = ldsA + tid * 8;
    short* lb = ldsB + tid * 8;

    for (int k0 = 0; k0 < K; k0 += 32) {
        gload_lds16(Ag + k0, la);
        gload_lds16(Ag + (size_t)64 * K + k0, la + 2048);
        gload_lds16(Bg + k0, lb);
        gload_lds16(Bg + (size_t)64 * K + k0, lb + 2048);
        __syncthreads();   // compiler emits vmcnt(0) drain before barrier
        bf16x8 af[4], bfr[4];
#pragma unroll
        for (int i = 0; i < 4; ++i)
            af[i] = *(const bf16x8*)&ldsA[(wrow + i * 16 + m) * 32 + quad * 8];
#pragma unroll
        for (int j = 0; j < 4; ++j)
            bfr[j] = *(const bf16x8*)&ldsB[(wcol + j * 16 + m) * 32 + quad * 8];
#pragma unroll
        for (int i = 0; i < 4; ++i)
#pragma unroll
            for (int j = 0; j < 4; ++j)
                acc[i][j] = __builtin_amdgcn_mfma_f32_16x16x32_bf16(
                    af[i], bfr[j], acc[i][j], 0, 0, 0);
        __syncthreads();
    }

    // epilogue: C/D layout col=lane&15, row=quad*4+reg  [m89/m91 verified]
#pragma unroll
    for (int i = 0; i < 4; ++i) {
#pragma unroll
        for (int reg = 0; reg < 4; ++reg) {
            int row = row0 + wrow + i * 16 + quad * 4 + reg;
#pragma unroll
            for (int j = 0; j < 4; ++j) {
                int col = col0 + wcol + j * 16 + m;
                float v = acc[i][j][reg];
                if (MODE == 0) {
                    ((float*)C0)[(size_t)row * N + col] = v;
                } else if (MODE == 1) {
                    float s = silu_f(v);
                    if (col < DINNER)
                        ((unsigned short*)C0)[(size_t)row * DINNER + col] = f2b(s);
                    else
                        ((float*)C1)[(size_t)row * DINNER + (col - DINNER)] = s;
                } else {
                    ((unsigned short*)C0)[(size_t)row * N + col] = f2b(v);
                }
            }
        }
    }
}

// ---------------------------------------------------------------------------
// dt = softplus(x @ dtw^T + bias), xsum = per-head sum. x is bf16.
// One block per (b,l) row; 8 threads per head.
// ---------------------------------------------------------------------------
__global__ __launch_bounds__(256) void dt_xsum_kernel(
    const unsigned short* __restrict__ x, const float* __restrict__ dtw,
    const float* __restrict__ dtb, float* __restrict__ dt,
    float* __restrict__ xsum) {
    __shared__ float xs[DINNER];
    int bl = blockIdx.x;
    const unsigned short* xr = x + (size_t)bl * DINNER;
    {
        int i0 = threadIdx.x * 8;                 // 256 thr x 8 = 2048
        ushort4 a = *(const ushort4*)&xr[i0];
        ushort4 b = *(const ushort4*)&xr[i0 + 4];
        xs[i0 + 0] = b2f(a.x); xs[i0 + 1] = b2f(a.y);
        xs[i0 + 2] = b2f(a.z); xs[i0 + 3] = b2f(a.w);
        xs[i0 + 4] = b2f(b.x); xs[i0 + 5] = b2f(b.y);
        xs[i0 + 6] = b2f(b.z); xs[i0 + 7] = b2f(b.w);
    }
    __syncthreads();

    int h = threadIdx.x >> 3, s = threadIdx.x & 7;
    float xa = 0.0f;
#pragma unroll
    for (int j = s; j < HEADDIM; j += 8) xa += xs[h * HEADDIM + j];

    float acc = 0.0f;
    const float* w = dtw + h * DINNER;
    for (int i = s; i < DINNER; i += 8) acc += xs[i] * w[i];

#pragma unroll
    for (int off = 1; off < 8; off <<= 1) {
        acc += __shfl_xor(acc, off);
        xa  += __shfl_xor(xa, off);
    }
    if (s == 0) {
        dt[bl * NHEADS + h]   = softplus_f(acc + dtb[h]);
        xsum[bl * NHEADS + h] = xa;
    }
}

// ---------------------------------------------------------------------------
// in-place RMS norm over 256-elem groups of bf16 bc. 4 waves = 4 groups/block.
// ---------------------------------------------------------------------------
__global__ __launch_bounds__(256) void rmsnorm_kernel(
    unsigned short* __restrict__ bc, const float* __restrict__ wB,
    const float* __restrict__ wC) {
    int g = blockIdx.x * 4 + (threadIdx.x >> 6);
    int lane = threadIdx.x & 63;
    int cb = g & 1;
    unsigned short* p = bc + (size_t)g * 256 + lane * 4;
    ushort4 v = *(ushort4*)p;
    float f0 = b2f(v.x), f1 = b2f(v.y), f2 = b2f(v.z), f3 = b2f(v.w);
    float ss = f0 * f0 + f1 * f1 + f2 * f2 + f3 * f3;
#pragma unroll
    for (int off = 1; off < 64; off <<= 1) ss += __shfl_xor(ss, off);
    float scale = rsqrtf(ss * (1.0f / 256.0f) + 1e-6f);
    const float* w = (cb ? wC : wB) + lane * 4;
    float4 wv = *(const float4*)w;
    ushort4 o = {f2b(f0 * scale * wv.x), f2b(f1 * scale * wv.y),
                 f2b(f2 * scale * wv.z), f2b(f3 * scale * wv.w)};
    *(ushort4*)p = o;
}

// ---------------------------------------------------------------------------
// complex bilinear scan. One block per (b,h), 128 threads = states. bc bf16.
// ---------------------------------------------------------------------------
__global__ __launch_bounds__(128) void scan_kernel(
    const unsigned short* __restrict__ bc, const float* __restrict__ dt,
    const float* __restrict__ xsum, const float* __restrict__ A,
    float* __restrict__ yredp) {
    int bh = blockIdx.x;
    int b = bh >> 5, h = bh & 31;
    int n = threadIdx.x;
    float ar = A[(h * DSTATE + n) * 2 + 0];
    float ai = A[(h * DSTATE + n) * 2 + 1];
    float hr = 0.0f, hi = 0.0f;

    const unsigned short* base = bc + (size_t)b * SEQ * 16384 + h * 512;
    const float* dtp = dt + b * SEQ * NHEADS + h;
    const float* xsp = xsum + b * SEQ * NHEADS + h;
    int wv = n >> 6, lane = n & 63;
    float* yp = yredp + ((size_t)(b * SEQ) * NHEADS + h) * 2 + wv;

    unsigned bw = *(const unsigned*)&base[n * 2];
    unsigned cw = *(const unsigned*)&base[256 + n * 2];
    float dtv = dtp[0], xsv = xsp[0];

    for (int l = 0; l < SEQ; ++l) {
        unsigned bwn = 0, cwn = 0;
        float dtn = 0.f, xsn = 0.f;
        if (l + 1 < SEQ) {
            const unsigned short* nb = base + (size_t)(l + 1) * 16384;
            bwn = *(const unsigned*)&nb[n * 2];
            cwn = *(const unsigned*)&nb[256 + n * 2];
            dtn = dtp[(l + 1) * NHEADS];
            xsn = xsp[(l + 1) * NHEADS];
        }
        float Br = b2f((unsigned short)(bw & 0xffff));
        float Bi = b2f((unsigned short)(bw >> 16));
        float Cr = b2f((unsigned short)(cw & 0xffff));
        float Ci = b2f((unsigned short)(cw >> 16));
        float hd = 0.5f * dtv;
        float ztr = ar * hd, zti = ai * hd;
        float denr = 1.0f - ztr;
        float s2 = 1.0f / (denr * denr + zti * zti);
        float invr = denr * s2, invi = zti * s2;     // 1/den
        float opr = 1.0f + ztr;
        float abr = opr * invr - zti * invi;
        float abi = opr * invi + zti * invr;
        float coef = dtv * xsv;
        float cr = coef * invr, ci = coef * invi;
        float ur = Br * cr - Bi * ci;
        float ui = Br * ci + Bi * cr;
        float nhr = abr * hr - abi * hi + ur;
        float nhi = abr * hi + abi * hr + ui;
        hr = nhr; hi = nhi;
        float y = Cr * hr - Ci * hi;
#pragma unroll
        for (int off = 1; off < 64; off <<= 1) y += __shfl_xor(y, off);
        if (lane == 0) yp[(size_t)l * (NHEADS * 2)] = y;
        bw = bwn; cw = cwn; dtv = dtn; xsv = xsn;
    }
}

// ---------------------------------------------------------------------------
// y = x * (yred + D[h]) * silu(z); x bf16, sz f32, y bf16.
// ---------------------------------------------------------------------------
__global__ __launch_bounds__(256) void yfuse_kernel(
    const unsigned short* __restrict__ x, const float* __restrict__ sz,
    const float* __restrict__ yredp, const float* __restrict__ Dv,
    unsigned short* __restrict__ y) {
    int i = (blockIdx.x * 256 + threadIdx.x) * 4;
    int r = i >> 11;
    int k = i & (DINNER - 1);
    int h = k >> 6;
    float yr = yredp[(r * NHEADS + h) * 2 + 0] +
               yredp[(r * NHEADS + h) * 2 + 1] + Dv[h];
    ushort4 xv = *(const ushort4*)&x[i];
    float4 zv = *(const float4*)&sz[i];
    ushort4 o = {f2b(b2f(xv.x) * yr * zv.x), f2b(b2f(xv.y) * yr * zv.y),
                 f2b(b2f(xv.z) * yr * zv.z), f2b(b2f(xv.w) * yr * zv.w)};
    *(ushort4*)&y[i] = o;
}

extern "C" void kernel_launch(void* const* d_in, const int* in_sizes, int n_in,
                              void* d_out, int out_size, void* d_ws, size_t ws_size,
                              hipStream_t stream) {
    const float* u   = (const float*)d_in[0];
    const float* ipw = (const float*)d_in[1];
    const float* dtw = (const float*)d_in[2];
    const float* dtb = (const float*)d_in[3];
    const float* xpw = (const float*)d_in[4];
    const float* A   = (const float*)d_in[5];
    const float* Dv  = (const float*)d_in[6];
    const float* wB  = (const float*)d_in[7];
    const float* wC  = (const float*)d_in[8];
    const float* opw = (const float*)d_in[9];
    float* out = (float*)d_out;
    char* ws = (char*)d_ws;

    unsigned short* u_b   = (unsigned short*)(ws + OFF_UB);
    unsigned short* w_xz  = (unsigned short*)(ws + OFF_WXZ);
    unsigned short* w_bc  = (unsigned short*)(ws + OFF_WBC);
    unsigned short* w_out = (unsigned short*)(ws + OFF_WOUT);
    unsigned short* x_b   = (unsigned short*)(ws + OFF_XB);
    unsigned short* y_b   = (unsigned short*)(ws + OFF_YB);
    unsigned short* bc    = (unsigned short*)(ws + OFF_BC);
    float* sz    = (float*)(ws + OFF_SZ);
    float* dt    = (float*)(ws + OFF_DT);
    float* xsum  = (float*)(ws + OFF_XS);
    float* yredp = (float*)(ws + OFF_YR);

    // bf16 conversions / packing (memory-bound, ~50 us total)
    f2b_kernel<<<4096, 256, 0, stream>>>(u, u_b);            // 4096x1024
    f2b_kernel<<<4096, 256, 0, stream>>>(ipw, w_xz);         // 4096x1024
    f2b_kernel<<<2048, 256, 0, stream>>>(opw, w_out);        // 1024x2048
    pack_xpw_kernel<<<32768, 256, 0, stream>>>(xpw, w_bc);   // 16384x2048

    // xz = u @ ipw^T, silu, split -> x (bf16), sz (f32)
    gemm_mfma<1024, 1><<<dim3(32, 32), 256, 0, stream>>>(u_b, w_xz, x_b, sz, 4096);
    dt_xsum_kernel<<<BLTOT, 256, 0, stream>>>(x_b, dtw, dtb, dt, xsum);
    // bc = x @ xpw_packed^T (bf16 out)
    gemm_mfma<2048, 2><<<dim3(128, 32), 256, 0, stream>>>(x_b, w_bc, bc, nullptr, 16384);
    rmsnorm_kernel<<<BLTOT * NHEADS * 2 / 4, 256, 0, stream>>>(bc, wB, wC);
    scan_kernel<<<BATCH * NHEADS, 128, 0, stream>>>(bc, dt, xsum, A, yredp);
    yfuse_kernel<<<BLTOT * DINNER / 4 / 256, 256, 0, stream>>>(x_b, sz, yredp, Dv, y_b);
    // out = y @ opw^T
    gemm_mfma<2048, 0><<<dim3(8, 32), 256, 0, stream>>>(y_b, w_out, out, nullptr, 1024);
}

// Round 3
// 879.594 us; speedup vs baseline: 6.4234x; 2.1521x over previous
//
#include <hip/hip_runtime.h>

#define BATCH   2
#define SEQ     2048
#define DMODEL  1024
#define DINNER  2048
#define NHEADS  32
#define HEADDIM 64
#define DSTATE  128
#define BLTOT   (BATCH * SEQ)          // 4096 rows
#define NCHUNK  32
#define CHUNK   64                     // SEQ / NCHUNK

// ---- workspace layout (byte offsets) --------------------------------------
#define OFF_UB   0ull                  // u bf16        4096x1024   8,388,608
#define OFF_WXZ  8388608ull            // in_proj bf16  4096x1024   8,388,608
#define OFF_WBC  16777216ull           // xpw packed    16384x2048 67,108,864
#define OFF_WOUT 83886080ull           // out_proj bf16 1024x2048   4,194,304
#define OFF_XB   88080384ull           // x bf16        4096x2048  16,777,216
#define OFF_YB   104857600ull          // y bf16        4096x2048  16,777,216
#define OFF_BC   121634816ull          // bc bf16       4096x16384 134,217,728
#define OFF_SZ   255852544ull          // silu(z) f32   4096x2048  33,554,432
#define OFF_DT   289406976ull          // dt f32        4096x32       524,288
#define OFF_XS   289931264ull          // xsum f32      4096x32       524,288
#define OFF_YR   290455552ull          // yred partials 4096x32x2   1,048,576
#define OFF_CA   291504128ull          // chunk A-prod  64x32x128 c  2,097,152
#define OFF_CS   293601280ull          // chunk state   64x32x128 c  2,097,152
#define OFF_HI   295698432ull          // chunk h_in    64x32x128 c  2,097,152
// total 297,795,584 B = 284 MB (round-0 used 337 MB OK, so ws_size suffices)

typedef __attribute__((ext_vector_type(8))) short bf16x8;
typedef __attribute__((ext_vector_type(4))) float f32x4;

__device__ __forceinline__ float b2f(unsigned short u) {
    return __uint_as_float(((unsigned)u) << 16);
}
__device__ __forceinline__ unsigned short f2b(float f) {
    unsigned x = __float_as_uint(f);
    unsigned r = (x + 0x7fffu + ((x >> 16) & 1u)) >> 16;   // RNE
    return (unsigned short)r;
}
__device__ __forceinline__ float silu_f(float v) {
    return v / (1.0f + __expf(-v));
}
__device__ __forceinline__ float softplus_f(float v) {
    return (v > 20.0f) ? v : log1pf(__expf(v));
}

__device__ __forceinline__ void gload_lds16(const void* g, void* l) {
    __builtin_amdgcn_global_load_lds(
        (const __attribute__((address_space(1))) unsigned int*)g,
        (__attribute__((address_space(3))) unsigned int*)l, 16, 0, 0);
}

// ---------------------------------------------------------------------------
// fp32 -> bf16 conversion (n divisible by 1024)
// ---------------------------------------------------------------------------
__global__ __launch_bounds__(256) void f2b_kernel(
    const float* __restrict__ in, unsigned short* __restrict__ out) {
    int i = (blockIdx.x * 256 + threadIdx.x) * 4;
    float4 v = *(const float4*)&in[i];
    ushort4 o = {f2b(v.x), f2b(v.y), f2b(v.z), f2b(v.w)};
    *(ushort4*)&out[i] = o;
}

// xpw: (16416, 2048) fp32 -> packed (16384, 2048) bf16, dropping per-head
// row 512. out col c <- src row (c/512)*513 + (c%512)
__global__ __launch_bounds__(256) void pack_xpw_kernel(
    const float* __restrict__ in, unsigned short* __restrict__ out) {
    int idx = blockIdx.x * 256 + threadIdx.x;
    int i = idx * 4;
    int c = i >> 11;
    int k = i & 2047;
    const float* src = in + ((size_t)(c >> 9) * 513 + (c & 511)) * 2048 + k;
    float4 v = *(const float4*)src;
    ushort4 o = {f2b(v.x), f2b(v.y), f2b(v.z), f2b(v.w)};
    *(ushort4*)&out[i] = o;
}

// ---------------------------------------------------------------------------
// MFMA GEMM (m97 structure): C[M,N] = A[M,K] @ B[N,K]^T, bf16 in, fp32 acc.
// 128x128 tile, BK=32, 256 thr = 4 waves, each wave 64x64 via 4x4 16x16x32.
// MODE 0: fp32 C0.  MODE 1: silu split (x bf16 / sz f32).  MODE 2: bf16 C0.
// ---------------------------------------------------------------------------
template <int K, int MODE>
__global__ __launch_bounds__(256) void gemm_mfma(
    const unsigned short* __restrict__ A, const unsigned short* __restrict__ B,
    void* __restrict__ C0, void* __restrict__ C1, int N) {
    __shared__ short ldsA[128 * 32];
    __shared__ short ldsB[128 * 32];
    int tid = threadIdx.x;
    int row0 = blockIdx.y * 128, col0 = blockIdx.x * 128;
    int lane = tid & 63, wave = tid >> 6;
    int wrow = (wave >> 1) * 64, wcol = (wave & 1) * 64;
    int m = lane & 15, quad = lane >> 4;

    f32x4 acc[4][4];
#pragma unroll
    for (int i = 0; i < 4; ++i)
#pragma unroll
        for (int j = 0; j < 4; ++j) acc[i][j] = (f32x4){0.f, 0.f, 0.f, 0.f};

    int r = tid >> 2, c8 = (tid & 3) * 8;
    const unsigned short* Ag = A + (size_t)(row0 + r) * K + c8;
    const unsigned short* Bg = B + (size_t)(col0 + r) * K + c8;
    short* la = ldsA + tid * 8;
    short* lb = ldsB + tid * 8;

    for (int k0 = 0; k0 < K; k0 += 32) {
        gload_lds16(Ag + k0, la);
        gload_lds16(Ag + (size_t)64 * K + k0, la + 2048);
        gload_lds16(Bg + k0, lb);
        gload_lds16(Bg + (size_t)64 * K + k0, lb + 2048);
        __syncthreads();
        bf16x8 af[4], bfr[4];
#pragma unroll
        for (int i = 0; i < 4; ++i)
            af[i] = *(const bf16x8*)&ldsA[(wrow + i * 16 + m) * 32 + quad * 8];
#pragma unroll
        for (int j = 0; j < 4; ++j)
            bfr[j] = *(const bf16x8*)&ldsB[(wcol + j * 16 + m) * 32 + quad * 8];
#pragma unroll
        for (int i = 0; i < 4; ++i)
#pragma unroll
            for (int j = 0; j < 4; ++j)
                acc[i][j] = __builtin_amdgcn_mfma_f32_16x16x32_bf16(
                    af[i], bfr[j], acc[i][j], 0, 0, 0);
        __syncthreads();
    }

#pragma unroll
    for (int i = 0; i < 4; ++i) {
#pragma unroll
        for (int reg = 0; reg < 4; ++reg) {
            int row = row0 + wrow + i * 16 + quad * 4 + reg;
#pragma unroll
            for (int j = 0; j < 4; ++j) {
                int col = col0 + wcol + j * 16 + m;
                float v = acc[i][j][reg];
                if (MODE == 0) {
                    ((float*)C0)[(size_t)row * N + col] = v;
                } else if (MODE == 1) {
                    float s = silu_f(v);
                    if (col < DINNER)
                        ((unsigned short*)C0)[(size_t)row * DINNER + col] = f2b(s);
                    else
                        ((float*)C1)[(size_t)row * DINNER + (col - DINNER)] = s;
                } else {
                    ((unsigned short*)C0)[(size_t)row * N + col] = f2b(v);
                }
            }
        }
    }
}

// ---------------------------------------------------------------------------
// dt = softplus(x @ dtw^T + bias), xsum = per-head sum. x is bf16.
// ---------------------------------------------------------------------------
__global__ __launch_bounds__(256) void dt_xsum_kernel(
    const unsigned short* __restrict__ x, const float* __restrict__ dtw,
    const float* __restrict__ dtb, float* __restrict__ dt,
    float* __restrict__ xsum) {
    __shared__ float xs[DINNER];
    int bl = blockIdx.x;
    const unsigned short* xr = x + (size_t)bl * DINNER;
    {
        int i0 = threadIdx.x * 8;
        ushort4 a = *(const ushort4*)&xr[i0];
        ushort4 b = *(const ushort4*)&xr[i0 + 4];
        xs[i0 + 0] = b2f(a.x); xs[i0 + 1] = b2f(a.y);
        xs[i0 + 2] = b2f(a.z); xs[i0 + 3] = b2f(a.w);
        xs[i0 + 4] = b2f(b.x); xs[i0 + 5] = b2f(b.y);
        xs[i0 + 6] = b2f(b.z); xs[i0 + 7] = b2f(b.w);
    }
    __syncthreads();

    int h = threadIdx.x >> 3, s = threadIdx.x & 7;
    float xa = 0.0f;
#pragma unroll
    for (int j = s; j < HEADDIM; j += 8) xa += xs[h * HEADDIM + j];

    float acc = 0.0f;
    const float* w = dtw + h * DINNER;
    for (int i = s; i < DINNER; i += 8) acc += xs[i] * w[i];

#pragma unroll
    for (int off = 1; off < 8; off <<= 1) {
        acc += __shfl_xor(acc, off);
        xa  += __shfl_xor(xa, off);
    }
    if (s == 0) {
        dt[bl * NHEADS + h]   = softplus_f(acc + dtb[h]);
        xsum[bl * NHEADS + h] = xa;
    }
}

// ---------------------------------------------------------------------------
// in-place RMS norm over 256-elem bf16 groups. 4 waves = 4 groups/block.
// ---------------------------------------------------------------------------
__global__ __launch_bounds__(256) void rmsnorm_kernel(
    unsigned short* __restrict__ bc, const float* __restrict__ wB,
    const float* __restrict__ wC) {
    int g = blockIdx.x * 4 + (threadIdx.x >> 6);
    int lane = threadIdx.x & 63;
    int cb = g & 1;
    unsigned short* p = bc + (size_t)g * 256 + lane * 4;
    ushort4 v = *(ushort4*)p;
    float f0 = b2f(v.x), f1 = b2f(v.y), f2 = b2f(v.z), f3 = b2f(v.w);
    float ss = f0 * f0 + f1 * f1 + f2 * f2 + f3 * f3;
#pragma unroll
    for (int off = 1; off < 64; off <<= 1) ss += __shfl_xor(ss, off);
    float scale = rsqrtf(ss * (1.0f / 256.0f) + 1e-6f);
    const float* w = (cb ? wC : wB) + lane * 4;
    float4 wv = *(const float4*)w;
    ushort4 o = {f2b(f0 * scale * wv.x), f2b(f1 * scale * wv.y),
                 f2b(f2 * scale * wv.z), f2b(f3 * scale * wv.w)};
    *(ushort4*)p = o;
}

// ---------------------------------------------------------------------------
// Per-(n,l) recurrence coefficients: abar (bilinear) and Bbar*x input term.
// ---------------------------------------------------------------------------
__device__ __forceinline__ void step_coefs(
    float ar, float ai, float dtv, float xsv, unsigned bw,
    float& abr, float& abi, float& ur, float& ui) {
    float Br = b2f((unsigned short)(bw & 0xffff));
    float Bi = b2f((unsigned short)(bw >> 16));
    float hd = 0.5f * dtv;
    float ztr = ar * hd, zti = ai * hd;
    float denr = 1.0f - ztr;
    float s2 = 1.0f / (denr * denr + zti * zti);
    float invr = denr * s2, invi = zti * s2;     // 1/(1-zt)
    float opr = 1.0f + ztr;
    abr = opr * invr - zti * invi;
    abi = opr * invi + zti * invr;
    float coef = dtv * xsv;
    float cr = coef * invr, ci = coef * invi;
    ur = Br * cr - Bi * ci;
    ui = Br * ci + Bi * cr;
}

// ---------------------------------------------------------------------------
// Scan pass 1: per (b,h,chunk,n) compute chunk-summary
//   P = prod abar_l   (complex),  S = local scan final state (h_in = 0).
// Grid: BATCH*NHEADS*NCHUNK blocks x 128 threads.
// ---------------------------------------------------------------------------
__global__ __launch_bounds__(128) void scan_pass1(
    const unsigned short* __restrict__ bc, const float* __restrict__ dt,
    const float* __restrict__ xsum, const float* __restrict__ A,
    float2* __restrict__ cA, float2* __restrict__ cS) {
    int blk = blockIdx.x;
    int bh = blk >> 5, c = blk & (NCHUNK - 1);
    int b = bh >> 5, h = bh & 31;
    int n = threadIdx.x;
    float ar = A[(h * DSTATE + n) * 2 + 0];
    float ai = A[(h * DSTATE + n) * 2 + 1];
    int l0 = c * CHUNK;
    const unsigned short* base = bc + ((size_t)(b * SEQ + l0)) * 16384 + h * 512;
    const float* dtp = dt + (b * SEQ + l0) * NHEADS + h;
    const float* xsp = xsum + (b * SEQ + l0) * NHEADS + h;

    float pr = 1.f, pi = 0.f, sr = 0.f, si = 0.f;
    for (int l = 0; l < CHUNK; ++l) {
        unsigned bw = *(const unsigned*)&base[(size_t)l * 16384 + n * 2];
        float dtv = dtp[l * NHEADS], xsv = xsp[l * NHEADS];
        float abr, abi, ur, ui;
        step_coefs(ar, ai, dtv, xsv, bw, abr, abi, ur, ui);
        float nsr = abr * sr - abi * si + ur;
        float nsi = abr * si + abi * sr + ui;
        sr = nsr; si = nsi;
        float npr = abr * pr - abi * pi;
        float npi = abr * pi + abi * pr;
        pr = npr; pi = npi;
    }
    size_t idx = ((size_t)bh * NCHUNK + c) * DSTATE + n;
    cA[idx] = {pr, pi};
    cS[idx] = {sr, si};
}

// ---------------------------------------------------------------------------
// Fix-up: sequential composition over the 32 chunk summaries per (b,h,n).
// h_in[c] = state entering chunk c.  Grid: 64 blocks x 128 threads.
// ---------------------------------------------------------------------------
__global__ __launch_bounds__(128) void scan_fixup(
    const float2* __restrict__ cA, const float2* __restrict__ cS,
    float2* __restrict__ hin) {
    int bh = blockIdx.x;
    int n = threadIdx.x;
    float hr = 0.f, hi = 0.f;
    for (int c = 0; c < NCHUNK; ++c) {
        size_t idx = ((size_t)bh * NCHUNK + c) * DSTATE + n;
        hin[idx] = {hr, hi};
        float2 a = cA[idx];
        float2 s = cS[idx];
        float nhr = a.x * hr - a.y * hi + s.x;
        float nhi = a.x * hi + a.y * hr + s.y;
        hr = nhr; hi = nhi;
    }
}

// ---------------------------------------------------------------------------
// Scan pass 2: re-run each chunk from h_in, reduce y over states.
// Grid: BATCH*NHEADS*NCHUNK blocks x 128 threads.
// ---------------------------------------------------------------------------
__global__ __launch_bounds__(128) void scan_pass2(
    const unsigned short* __restrict__ bc, const float* __restrict__ dt,
    const float* __restrict__ xsum, const float* __restrict__ A,
    const float2* __restrict__ hin, float* __restrict__ yredp) {
    int blk = blockIdx.x;
    int bh = blk >> 5, c = blk & (NCHUNK - 1);
    int b = bh >> 5, h = bh & 31;
    int n = threadIdx.x;
    float ar = A[(h * DSTATE + n) * 2 + 0];
    float ai = A[(h * DSTATE + n) * 2 + 1];
    int l0 = c * CHUNK;
    const unsigned short* base = bc + ((size_t)(b * SEQ + l0)) * 16384 + h * 512;
    const float* dtp = dt + (b * SEQ + l0) * NHEADS + h;
    const float* xsp = xsum + (b * SEQ + l0) * NHEADS + h;
    int wv = n >> 6, lane = n & 63;
    float* yp = yredp + ((size_t)(b * SEQ + l0) * NHEADS + h) * 2 + wv;

    float2 h0 = hin[((size_t)bh * NCHUNK + c) * DSTATE + n];
    float hr = h0.x, hi = h0.y;
    for (int l = 0; l < CHUNK; ++l) {
        unsigned bw = *(const unsigned*)&base[(size_t)l * 16384 + n * 2];
        unsigned cw = *(const unsigned*)&base[(size_t)l * 16384 + 256 + n * 2];
        float dtv = dtp[l * NHEADS], xsv = xsp[l * NHEADS];
        float abr, abi, ur, ui;
        step_coefs(ar, ai, dtv, xsv, bw, abr, abi, ur, ui);
        float nhr = abr * hr - abi * hi + ur;
        float nhi = abr * hi + abi * hr + ui;
        hr = nhr; hi = nhi;
        float Cr = b2f((unsigned short)(cw & 0xffff));
        float Ci = b2f((unsigned short)(cw >> 16));
        float y = Cr * hr - Ci * hi;
#pragma unroll
        for (int off = 1; off < 64; off <<= 1) y += __shfl_xor(y, off);
        if (lane == 0) yp[(size_t)l * (NHEADS * 2)] = y;
    }
}

// ---------------------------------------------------------------------------
// y = x * (yred + D[h]) * silu(z); x bf16, sz f32, y bf16.
// ---------------------------------------------------------------------------
__global__ __launch_bounds__(256) void yfuse_kernel(
    const unsigned short* __restrict__ x, const float* __restrict__ sz,
    const float* __restrict__ yredp, const float* __restrict__ Dv,
    unsigned short* __restrict__ y) {
    int i = (blockIdx.x * 256 + threadIdx.x) * 4;
    int r = i >> 11;
    int k = i & (DINNER - 1);
    int h = k >> 6;
    float yr = yredp[(r * NHEADS + h) * 2 + 0] +
               yredp[(r * NHEADS + h) * 2 + 1] + Dv[h];
    ushort4 xv = *(const ushort4*)&x[i];
    float4 zv = *(const float4*)&sz[i];
    ushort4 o = {f2b(b2f(xv.x) * yr * zv.x), f2b(b2f(xv.y) * yr * zv.y),
                 f2b(b2f(xv.z) * yr * zv.z), f2b(b2f(xv.w) * yr * zv.w)};
    *(ushort4*)&y[i] = o;
}

extern "C" void kernel_launch(void* const* d_in, const int* in_sizes, int n_in,
                              void* d_out, int out_size, void* d_ws, size_t ws_size,
                              hipStream_t stream) {
    const float* u   = (const float*)d_in[0];
    const float* ipw = (const float*)d_in[1];
    const float* dtw = (const float*)d_in[2];
    const float* dtb = (const float*)d_in[3];
    const float* xpw = (const float*)d_in[4];
    const float* A   = (const float*)d_in[5];
    const float* Dv  = (const float*)d_in[6];
    const float* wB  = (const float*)d_in[7];
    const float* wC  = (const float*)d_in[8];
    const float* opw = (const float*)d_in[9];
    float* out = (float*)d_out;
    char* ws = (char*)d_ws;

    unsigned short* u_b   = (unsigned short*)(ws + OFF_UB);
    unsigned short* w_xz  = (unsigned short*)(ws + OFF_WXZ);
    unsigned short* w_bc  = (unsigned short*)(ws + OFF_WBC);
    unsigned short* w_out = (unsigned short*)(ws + OFF_WOUT);
    unsigned short* x_b   = (unsigned short*)(ws + OFF_XB);
    unsigned short* y_b   = (unsigned short*)(ws + OFF_YB);
    unsigned short* bc    = (unsigned short*)(ws + OFF_BC);
    float* sz    = (float*)(ws + OFF_SZ);
    float* dt    = (float*)(ws + OFF_DT);
    float* xsum  = (float*)(ws + OFF_XS);
    float* yredp = (float*)(ws + OFF_YR);
    float2* cA   = (float2*)(ws + OFF_CA);
    float2* cS   = (float2*)(ws + OFF_CS);
    float2* hin  = (float2*)(ws + OFF_HI);

    f2b_kernel<<<4096, 256, 0, stream>>>(u, u_b);
    f2b_kernel<<<4096, 256, 0, stream>>>(ipw, w_xz);
    f2b_kernel<<<2048, 256, 0, stream>>>(opw, w_out);
    pack_xpw_kernel<<<32768, 256, 0, stream>>>(xpw, w_bc);

    gemm_mfma<1024, 1><<<dim3(32, 32), 256, 0, stream>>>(u_b, w_xz, x_b, sz, 4096);
    dt_xsum_kernel<<<BLTOT, 256, 0, stream>>>(x_b, dtw, dtb, dt, xsum);
    gemm_mfma<2048, 2><<<dim3(128, 32), 256, 0, stream>>>(x_b, w_bc, bc, nullptr, 16384);
    rmsnorm_kernel<<<BLTOT * NHEADS * 2 / 4, 256, 0, stream>>>(bc, wB, wC);

    scan_pass1<<<BATCH * NHEADS * NCHUNK, 128, 0, stream>>>(bc, dt, xsum, A, cA, cS);
    scan_fixup<<<BATCH * NHEADS, 128, 0, stream>>>(cA, cS, hin);
    scan_pass2<<<BATCH * NHEADS * NCHUNK, 128, 0, stream>>>(bc, dt, xsum, A, hin, yredp);

    yfuse_kernel<<<BLTOT * DINNER / 4 / 256, 256, 0, stream>>>(x_b, sz, yredp, Dv, y_b);
    gemm_mfma<2048, 0><<<dim3(8, 32), 256, 0, stream>>>(y_b, w_out, out, nullptr, 1024);
}

// Round 4
// 837.521 us; speedup vs baseline: 6.7461x; 1.0502x over previous
//
#include <hip/hip_runtime.h>

#define BATCH   2
#define SEQ     2048
#define DMODEL  1024
#define DINNER  2048
#define NHEADS  32
#define HEADDIM 64
#define DSTATE  128
#define BLTOT   (BATCH * SEQ)          // 4096 rows
#define NCHUNK  32
#define CHUNK   64                     // SEQ / NCHUNK

// ---- workspace layout (byte offsets) --------------------------------------
#define OFF_UB   0ull                  // u bf16        4096x1024   8,388,608
#define OFF_WXZ  8388608ull            // in_proj bf16  4096x1024   8,388,608
#define OFF_WBC  16777216ull           // xpw packed    16384x2048 67,108,864
#define OFF_WOUT 83886080ull           // out_proj bf16 1024x2048   4,194,304
#define OFF_XB   88080384ull           // x bf16        4096x2048  16,777,216
#define OFF_YB   104857600ull          // y bf16        4096x2048  16,777,216
#define OFF_BC   121634816ull          // bc bf16 raw   4096x16384 134,217,728
#define OFF_SZ   255852544ull          // silu(z) bf16  4096x2048  16,777,216
#define OFF_DT   272629760ull          // dt f32        4096x32       524,288
#define OFF_XS   273154048ull          // xsum f32      4096x32       524,288
#define OFF_YR   273678336ull          // yred f32      4096x32       524,288
#define OFF_CA   274202624ull          // chunk A-prod  64x32x128 c  2,097,152
#define OFF_CS   276299776ull          // chunk state   64x32x128 c  2,097,152
#define OFF_HI   278396928ull          // chunk h_in    64x32x128 c  2,097,152
// total 280,494,080 B = 268 MB

typedef __attribute__((ext_vector_type(8))) short bf16x8;
typedef __attribute__((ext_vector_type(4))) float f32x4;

__device__ __forceinline__ float b2f(unsigned short u) {
    return __uint_as_float(((unsigned)u) << 16);
}
__device__ __forceinline__ unsigned short f2b(float f) {
    unsigned x = __float_as_uint(f);
    unsigned r = (x + 0x7fffu + ((x >> 16) & 1u)) >> 16;   // RNE
    return (unsigned short)r;
}
__device__ __forceinline__ float silu_f(float v) {
    return v / (1.0f + __expf(-v));
}
__device__ __forceinline__ float softplus_f(float v) {
    return (v > 20.0f) ? v : log1pf(__expf(v));
}

__device__ __forceinline__ void gload_lds16(const void* g, void* l) {
    __builtin_amdgcn_global_load_lds(
        (const __attribute__((address_space(1))) unsigned int*)g,
        (__attribute__((address_space(3))) unsigned int*)l, 16, 0, 0);
}

// ---------------------------------------------------------------------------
// One-shot conversions: u/ipw/opw fp32->bf16, xpw fp32->packed bf16
// (drops per-head row 512: out col c <- src row (c/512)*513 + (c%512)).
// Work unit = 4 floats. Regions: u 1048576 | ipw 1048576 | opw 524288 |
// xpw 8388608 groups. grid = 43008 * 256.
// ---------------------------------------------------------------------------
__global__ __launch_bounds__(256) void conv_all_kernel(
    const float* __restrict__ u, const float* __restrict__ ipw,
    const float* __restrict__ opw, const float* __restrict__ xpw,
    unsigned short* __restrict__ u_b, unsigned short* __restrict__ w_xz,
    unsigned short* __restrict__ w_out, unsigned short* __restrict__ w_bc) {
    long idx = (long)blockIdx.x * 256 + threadIdx.x;
    if (idx >= 2621440L) {                       // xpw pack region
        long e = (idx - 2621440L) * 4;
        long c = e >> 11, k = e & 2047;
        const float* s = xpw + ((c >> 9) * 513 + (c & 511)) * 2048 + k;
        float4 v = *(const float4*)s;
        ushort4 o = {f2b(v.x), f2b(v.y), f2b(v.z), f2b(v.w)};
        *(ushort4*)&w_bc[e] = o;
        return;
    }
    const float* src;
    unsigned short* dst;
    long i;
    if (idx < 1048576L)      { src = u;   dst = u_b;   i = idx; }
    else if (idx < 2097152L) { src = ipw; dst = w_xz;  i = idx - 1048576L; }
    else                     { src = opw; dst = w_out; i = idx - 2097152L; }
    float4 v = *(const float4*)&src[i * 4];
    ushort4 o = {f2b(v.x), f2b(v.y), f2b(v.z), f2b(v.w)};
    *(ushort4*)&dst[i * 4] = o;
}

// ---------------------------------------------------------------------------
// MFMA GEMM (m97 structure): C[M,N] = A[M,K] @ B[N,K]^T, bf16 in, fp32 acc.
// 128x128 tile, BK=32, 256 thr = 4 waves, wave 64x64 via 4x4 16x16x32.
// MODE 0: fp32 C0.
// MODE 1: silu; x-half -> bf16 C0 + per-head row-sum -> xsum (C2);
//         z-half -> bf16 C1.
// MODE 2: bf16 C0.
// ---------------------------------------------------------------------------
template <int K, int MODE>
__global__ __launch_bounds__(256) void gemm_mfma(
    const unsigned short* __restrict__ A, const unsigned short* __restrict__ B,
    void* __restrict__ C0, void* __restrict__ C1, float* __restrict__ C2,
    int N) {
    __shared__ short ldsA[128 * 32];
    __shared__ short ldsB[128 * 32];
    int tid = threadIdx.x;
    int row0 = blockIdx.y * 128, col0 = blockIdx.x * 128;
    int lane = tid & 63, wave = tid >> 6;
    int wrow = (wave >> 1) * 64, wcol = (wave & 1) * 64;
    int m = lane & 15, quad = lane >> 4;

    f32x4 acc[4][4];
#pragma unroll
    for (int i = 0; i < 4; ++i)
#pragma unroll
        for (int j = 0; j < 4; ++j) acc[i][j] = (f32x4){0.f, 0.f, 0.f, 0.f};

    int r = tid >> 2, c8 = (tid & 3) * 8;
    const unsigned short* Ag = A + (size_t)(row0 + r) * K + c8;
    const unsigned short* Bg = B + (size_t)(col0 + r) * K + c8;
    short* la = ldsA + tid * 8;
    short* lb = ldsB + tid * 8;

    for (int k0 = 0; k0 < K; k0 += 32) {
        gload_lds16(Ag + k0, la);
        gload_lds16(Ag + (size_t)64 * K + k0, la + 2048);
        gload_lds16(Bg + k0, lb);
        gload_lds16(Bg + (size_t)64 * K + k0, lb + 2048);
        __syncthreads();
        bf16x8 af[4], bfr[4];
#pragma unroll
        for (int i = 0; i < 4; ++i)
            af[i] = *(const bf16x8*)&ldsA[(wrow + i * 16 + m) * 32 + quad * 8];
#pragma unroll
        for (int j = 0; j < 4; ++j)
            bfr[j] = *(const bf16x8*)&ldsB[(wcol + j * 16 + m) * 32 + quad * 8];
#pragma unroll
        for (int i = 0; i < 4; ++i)
#pragma unroll
            for (int j = 0; j < 4; ++j)
                acc[i][j] = __builtin_amdgcn_mfma_f32_16x16x32_bf16(
                    af[i], bfr[j], acc[i][j], 0, 0, 0);
        __syncthreads();
    }

    // epilogue: C/D layout col=lane&15, row=quad*4+reg  [m89/m91 verified]
    if (MODE == 1) {
        bool isx = (col0 < DINNER);          // block-uniform
        if (isx) {
            int head = (col0 + wcol) >> 6;   // wave's 64 cols = one head
            float ssum[4][4];
#pragma unroll
            for (int i = 0; i < 4; ++i)
#pragma unroll
                for (int reg = 0; reg < 4; ++reg) ssum[i][reg] = 0.f;
#pragma unroll
            for (int i = 0; i < 4; ++i)
#pragma unroll
                for (int reg = 0; reg < 4; ++reg) {
                    int row = row0 + wrow + i * 16 + quad * 4 + reg;
#pragma unroll
                    for (int j = 0; j < 4; ++j) {
                        int col = col0 + wcol + j * 16 + m;
                        float s = silu_f(acc[i][j][reg]);
                        ((unsigned short*)C0)[(size_t)row * DINNER + col] = f2b(s);
                        ssum[i][reg] += s;
                    }
                }
            // reduce over the 16 m-lanes (lane bits 0..3)
#pragma unroll
            for (int i = 0; i < 4; ++i)
#pragma unroll
                for (int reg = 0; reg < 4; ++reg) {
                    float s = ssum[i][reg];
                    s += __shfl_xor(s, 1);
                    s += __shfl_xor(s, 2);
                    s += __shfl_xor(s, 4);
                    s += __shfl_xor(s, 8);
                    if (m == 0) {
                        int row = row0 + wrow + i * 16 + quad * 4 + reg;
                        C2[(size_t)row * NHEADS + head] = s;
                    }
                }
        } else {
#pragma unroll
            for (int i = 0; i < 4; ++i)
#pragma unroll
                for (int reg = 0; reg < 4; ++reg) {
                    int row = row0 + wrow + i * 16 + quad * 4 + reg;
#pragma unroll
                    for (int j = 0; j < 4; ++j) {
                        int col = col0 + wcol + j * 16 + m - DINNER;
                        float s = silu_f(acc[i][j][reg]);
                        ((unsigned short*)C1)[(size_t)row * DINNER + col] = f2b(s);
                    }
                }
        }
    } else {
#pragma unroll
        for (int i = 0; i < 4; ++i)
#pragma unroll
            for (int reg = 0; reg < 4; ++reg) {
                int row = row0 + wrow + i * 16 + quad * 4 + reg;
#pragma unroll
                for (int j = 0; j < 4; ++j) {
                    int col = col0 + wcol + j * 16 + m;
                    float v = acc[i][j][reg];
                    if (MODE == 0)
                        ((float*)C0)[(size_t)row * N + col] = v;
                    else
                        ((unsigned short*)C0)[(size_t)row * N + col] = f2b(v);
                }
            }
    }
}

// ---------------------------------------------------------------------------
// dt = softplus(x @ dtw^T + bias). 16 rows/block, LDS-tiled (pad +4 breaks
// the same-bank broadcast-miss: stride 132 -> h*4+k spread over banks).
// thread = (row = t>>4, heads h0 = t&15 and h0+16).
// ---------------------------------------------------------------------------
__global__ __launch_bounds__(256) void dt_kernel(
    const unsigned short* __restrict__ x, const float* __restrict__ dtw,
    const float* __restrict__ dtb, float* __restrict__ dt) {
    __shared__ float xs[16][132];
    __shared__ float ws[32][132];
    int r0 = blockIdx.x * 16;
    int t = threadIdx.x;
    int lrow = t >> 4, lc8 = (t & 15) * 8;   // x staging
    int lh = t >> 3, lc16 = (t & 7) * 16;    // w staging
    int row = t >> 4, h0 = t & 15;           // compute
    float acc0 = 0.f, acc1 = 0.f;

    for (int kc = 0; kc < DINNER; kc += 128) {
        ushort4 a = *(const ushort4*)&x[(size_t)(r0 + lrow) * DINNER + kc + lc8];
        ushort4 b = *(const ushort4*)&x[(size_t)(r0 + lrow) * DINNER + kc + lc8 + 4];
        xs[lrow][lc8 + 0] = b2f(a.x); xs[lrow][lc8 + 1] = b2f(a.y);
        xs[lrow][lc8 + 2] = b2f(a.z); xs[lrow][lc8 + 3] = b2f(a.w);
        xs[lrow][lc8 + 4] = b2f(b.x); xs[lrow][lc8 + 5] = b2f(b.y);
        xs[lrow][lc8 + 6] = b2f(b.z); xs[lrow][lc8 + 7] = b2f(b.w);
#pragma unroll
        for (int q = 0; q < 4; ++q) {
            float4 w = *(const float4*)&dtw[(size_t)lh * DINNER + kc + lc16 + q * 4];
            *(float4*)&ws[lh][lc16 + q * 4] = w;
        }
        __syncthreads();
#pragma unroll
        for (int k = 0; k < 128; k += 4) {
            float4 xv = *(const float4*)&xs[row][k];
            float4 w0 = *(const float4*)&ws[h0][k];
            float4 w1 = *(const float4*)&ws[h0 + 16][k];
            acc0 += xv.x * w0.x + xv.y * w0.y + xv.z * w0.z + xv.w * w0.w;
            acc1 += xv.x * w1.x + xv.y * w1.y + xv.z * w1.z + xv.w * w1.w;
        }
        __syncthreads();
    }
    dt[(size_t)(r0 + row) * NHEADS + h0]      = softplus_f(acc0 + dtb[h0]);
    dt[(size_t)(r0 + row) * NHEADS + h0 + 16] = softplus_f(acc1 + dtb[h0 + 16]);
}

// ---------------------------------------------------------------------------
// Recurrence coefficients from NORMALIZED B. abar = (1+zt)/(1-zt),
// u = Bn * dt*xsum/(1-zt).
// ---------------------------------------------------------------------------
__device__ __forceinline__ void coefs(
    float ar, float ai, float dtv, float xsv, float Br, float Bi,
    float& abr, float& abi, float& ur, float& ui) {
    float hd = 0.5f * dtv;
    float ztr = ar * hd, zti = ai * hd;
    float denr = 1.0f - ztr;
    float s2 = 1.0f / (denr * denr + zti * zti);
    float invr = denr * s2, invi = zti * s2;     // 1/(1-zt)
    float opr = 1.0f + ztr;
    abr = opr * invr - zti * invi;
    abi = opr * invi + zti * invr;
    float coef = dtv * xsv;
    float cr = coef * invr, ci = coef * invi;
    ur = Br * cr - Bi * ci;
    ui = Br * ci + Bi * cr;
}

// ---------------------------------------------------------------------------
// Scan pass 1: chunk summaries P = prod(abar), S = local state. Inline B-norm:
// one wave holds the whole 256-elem norm group (2 states/thread).
// Grid: BATCH*NHEADS*NCHUNK x 64 thr.
// ---------------------------------------------------------------------------
__global__ __launch_bounds__(64) void scan_pass1(
    const unsigned short* __restrict__ bc, const float* __restrict__ dt,
    const float* __restrict__ xsum, const float* __restrict__ A,
    const float* __restrict__ wB, float2* __restrict__ cA,
    float2* __restrict__ cS) {
    int blk = blockIdx.x;
    int bh = blk >> 5, c = blk & (NCHUNK - 1);
    int b = bh >> 5, h = bh & 31;
    int t = threadIdx.x;                         // states n=2t, 2t+1
    float4 av = *(const float4*)&A[(h * DSTATE + 2 * t) * 2];
    float4 wv = *(const float4*)&wB[4 * t];
    int l0 = c * CHUNK;
    const unsigned short* base = bc + ((size_t)(b * SEQ + l0)) * 16384 + h * 512;
    const float* dtp = dt + (b * SEQ + l0) * NHEADS + h;
    const float* xsp = xsum + (b * SEQ + l0) * NHEADS + h;

    float pr0 = 1.f, pi0 = 0.f, sr0 = 0.f, si0 = 0.f;
    float pr1 = 1.f, pi1 = 0.f, sr1 = 0.f, si1 = 0.f;
    for (int l = 0; l < CHUNK; ++l) {
        uint2 bw = *(const uint2*)&base[(size_t)l * 16384 + 4 * t];
        float Br0 = b2f((unsigned short)(bw.x & 0xffff));
        float Bi0 = b2f((unsigned short)(bw.x >> 16));
        float Br1 = b2f((unsigned short)(bw.y & 0xffff));
        float Bi1 = b2f((unsigned short)(bw.y >> 16));
        float ss = Br0 * Br0 + Bi0 * Bi0 + Br1 * Br1 + Bi1 * Bi1;
#pragma unroll
        for (int off = 1; off < 64; off <<= 1) ss += __shfl_xor(ss, off);
        float scale = rsqrtf(ss * (1.0f / 256.0f) + 1e-6f);
        Br0 *= scale * wv.x; Bi0 *= scale * wv.y;
        Br1 *= scale * wv.z; Bi1 *= scale * wv.w;
        float dtv = dtp[l * NHEADS], xsv = xsp[l * NHEADS];
        float abr, abi, ur, ui;
        coefs(av.x, av.y, dtv, xsv, Br0, Bi0, abr, abi, ur, ui);
        float ns = abr * sr0 - abi * si0 + ur;
        float nsi = abr * si0 + abi * sr0 + ui;
        sr0 = ns; si0 = nsi;
        float np = abr * pr0 - abi * pi0;
        float npi = abr * pi0 + abi * pr0;
        pr0 = np; pi0 = npi;
        coefs(av.z, av.w, dtv, xsv, Br1, Bi1, abr, abi, ur, ui);
        ns = abr * sr1 - abi * si1 + ur;
        nsi = abr * si1 + abi * sr1 + ui;
        sr1 = ns; si1 = nsi;
        np = abr * pr1 - abi * pi1;
        npi = abr * pi1 + abi * pr1;
        pr1 = np; pi1 = npi;
    }
    size_t idx = ((size_t)bh * NCHUNK + c) * DSTATE + 2 * t;
    *(float4*)&cA[idx] = (float4){pr0, pi0, pr1, pi1};
    *(float4*)&cS[idx] = (float4){sr0, si0, sr1, si1};
}

// ---------------------------------------------------------------------------
// Fix-up: sequential composition of 32 chunk summaries per (b,h,n).
// ---------------------------------------------------------------------------
__global__ __launch_bounds__(128) void scan_fixup(
    const float2* __restrict__ cA, const float2* __restrict__ cS,
    float2* __restrict__ hin) {
    int bh = blockIdx.x;
    int n = threadIdx.x;
    float hr = 0.f, hi = 0.f;
    for (int c = 0; c < NCHUNK; ++c) {
        size_t idx = ((size_t)bh * NCHUNK + c) * DSTATE + n;
        hin[idx] = {hr, hi};
        float2 a = cA[idx];
        float2 s = cS[idx];
        float nhr = a.x * hr - a.y * hi + s.x;
        float nhi = a.x * hi + a.y * hr + s.y;
        hr = nhr; hi = nhi;
    }
}

// ---------------------------------------------------------------------------
// Scan pass 2: replay chunk from h_in, inline B+C norm, y = sum Re(C*h).
// Grid: BATCH*NHEADS*NCHUNK x 64 thr.
// ---------------------------------------------------------------------------
__global__ __launch_bounds__(64) void scan_pass2(
    const unsigned short* __restrict__ bc, const float* __restrict__ dt,
    const float* __restrict__ xsum, const float* __restrict__ A,
    const float* __restrict__ wB, const float* __restrict__ wC,
    const float2* __restrict__ hin, float* __restrict__ yredp) {
    int blk = blockIdx.x;
    int bh = blk >> 5, c = blk & (NCHUNK - 1);
    int b = bh >> 5, h = bh & 31;
    int t = threadIdx.x;
    float4 av = *(const float4*)&A[(h * DSTATE + 2 * t) * 2];
    float4 wbv = *(const float4*)&wB[4 * t];
    float4 wcv = *(const float4*)&wC[4 * t];
    int l0 = c * CHUNK;
    const unsigned short* base = bc + ((size_t)(b * SEQ + l0)) * 16384 + h * 512;
    const float* dtp = dt + (b * SEQ + l0) * NHEADS + h;
    const float* xsp = xsum + (b * SEQ + l0) * NHEADS + h;
    float* yp = yredp + (size_t)(b * SEQ + l0) * NHEADS + h;

    float4 h0v = *(const float4*)&hin[((size_t)bh * NCHUNK + c) * DSTATE + 2 * t];
    float hr0 = h0v.x, hi0 = h0v.y, hr1 = h0v.z, hi1 = h0v.w;

    for (int l = 0; l < CHUNK; ++l) {
        uint2 bw = *(const uint2*)&base[(size_t)l * 16384 + 4 * t];
        uint2 cw = *(const uint2*)&base[(size_t)l * 16384 + 256 + 4 * t];
        float Br0 = b2f((unsigned short)(bw.x & 0xffff));
        float Bi0 = b2f((unsigned short)(bw.x >> 16));
        float Br1 = b2f((unsigned short)(bw.y & 0xffff));
        float Bi1 = b2f((unsigned short)(bw.y >> 16));
        float Cr0 = b2f((unsigned short)(cw.x & 0xffff));
        float Ci0 = b2f((unsigned short)(cw.x >> 16));
        float Cr1 = b2f((unsigned short)(cw.y & 0xffff));
        float Ci1 = b2f((unsigned short)(cw.y >> 16));
        float ssB = Br0 * Br0 + Bi0 * Bi0 + Br1 * Br1 + Bi1 * Bi1;
        float ssC = Cr0 * Cr0 + Ci0 * Ci0 + Cr1 * Cr1 + Ci1 * Ci1;
#pragma unroll
        for (int off = 1; off < 64; off <<= 1) {
            ssB += __shfl_xor(ssB, off);
            ssC += __shfl_xor(ssC, off);
        }
        float sB = rsqrtf(ssB * (1.0f / 256.0f) + 1e-6f);
        float sC = rsqrtf(ssC * (1.0f / 256.0f) + 1e-6f);
        Br0 *= sB * wbv.x; Bi0 *= sB * wbv.y;
        Br1 *= sB * wbv.z; Bi1 *= sB * wbv.w;
        Cr0 *= sC * wcv.x; Ci0 *= sC * wcv.y;
        Cr1 *= sC * wcv.z; Ci1 *= sC * wcv.w;
        float dtv = dtp[l * NHEADS], xsv = xsp[l * NHEADS];
        float abr, abi, ur, ui;
        coefs(av.x, av.y, dtv, xsv, Br0, Bi0, abr, abi, ur, ui);
        float nhr = abr * hr0 - abi * hi0 + ur;
        float nhi = abr * hi0 + abi * hr0 + ui;
        hr0 = nhr; hi0 = nhi;
        coefs(av.z, av.w, dtv, xsv, Br1, Bi1, abr, abi, ur, ui);
        nhr = abr * hr1 - abi * hi1 + ur;
        nhi = abr * hi1 + abi * hr1 + ui;
        hr1 = nhr; hi1 = nhi;
        float y = Cr0 * hr0 - Ci0 * hi0 + Cr1 * hr1 - Ci1 * hi1;
#pragma unroll
        for (int off = 1; off < 64; off <<= 1) y += __shfl_xor(y, off);
        if (t == 0) yp[(size_t)l * NHEADS] = y;
    }
}

// ---------------------------------------------------------------------------
// y = x * (yred + D[h]) * silu(z); x bf16, sz bf16, y bf16.
// ---------------------------------------------------------------------------
__global__ __launch_bounds__(256) void yfuse_kernel(
    const unsigned short* __restrict__ x, const unsigned short* __restrict__ sz,
    const float* __restrict__ yredp, const float* __restrict__ Dv,
    unsigned short* __restrict__ y) {
    int i = (blockIdx.x * 256 + threadIdx.x) * 4;
    int r = i >> 11;
    int k = i & (DINNER - 1);
    int h = k >> 6;
    float yr = yredp[(size_t)r * NHEADS + h] + Dv[h];
    ushort4 xv = *(const ushort4*)&x[i];
    ushort4 zv = *(const ushort4*)&sz[i];
    ushort4 o = {f2b(b2f(xv.x) * yr * b2f(zv.x)),
                 f2b(b2f(xv.y) * yr * b2f(zv.y)),
                 f2b(b2f(xv.z) * yr * b2f(zv.z)),
                 f2b(b2f(xv.w) * yr * b2f(zv.w))};
    *(ushort4*)&y[i] = o;
}

extern "C" void kernel_launch(void* const* d_in, const int* in_sizes, int n_in,
                              void* d_out, int out_size, void* d_ws, size_t ws_size,
                              hipStream_t stream) {
    const float* u   = (const float*)d_in[0];
    const float* ipw = (const float*)d_in[1];
    const float* dtw = (const float*)d_in[2];
    const float* dtb = (const float*)d_in[3];
    const float* xpw = (const float*)d_in[4];
    const float* A   = (const float*)d_in[5];
    const float* Dv  = (const float*)d_in[6];
    const float* wB  = (const float*)d_in[7];
    const float* wC  = (const float*)d_in[8];
    const float* opw = (const float*)d_in[9];
    float* out = (float*)d_out;
    char* ws = (char*)d_ws;

    unsigned short* u_b   = (unsigned short*)(ws + OFF_UB);
    unsigned short* w_xz  = (unsigned short*)(ws + OFF_WXZ);
    unsigned short* w_bc  = (unsigned short*)(ws + OFF_WBC);
    unsigned short* w_out = (unsigned short*)(ws + OFF_WOUT);
    unsigned short* x_b   = (unsigned short*)(ws + OFF_XB);
    unsigned short* y_b   = (unsigned short*)(ws + OFF_YB);
    unsigned short* bc    = (unsigned short*)(ws + OFF_BC);
    unsigned short* sz    = (unsigned short*)(ws + OFF_SZ);
    float* dt    = (float*)(ws + OFF_DT);
    float* xsum  = (float*)(ws + OFF_XS);
    float* yredp = (float*)(ws + OFF_YR);
    float2* cA   = (float2*)(ws + OFF_CA);
    float2* cS   = (float2*)(ws + OFF_CS);
    float2* hin  = (float2*)(ws + OFF_HI);

    conv_all_kernel<<<43008, 256, 0, stream>>>(u, ipw, opw, xpw,
                                               u_b, w_xz, w_out, w_bc);

    // xz = u @ ipw^T, silu, split -> x bf16 (+ xsum epilogue) / sz bf16
    gemm_mfma<1024, 1><<<dim3(32, 32), 256, 0, stream>>>(
        u_b, w_xz, x_b, sz, xsum, 4096);
    dt_kernel<<<BLTOT / 16, 256, 0, stream>>>(x_b, dtw, dtb, dt);
    // bc = x @ xpw_packed^T (raw bf16; norm applied inline in scan)
    gemm_mfma<2048, 2><<<dim3(128, 32), 256, 0, stream>>>(
        x_b, w_bc, bc, nullptr, nullptr, 16384);

    scan_pass1<<<BATCH * NHEADS * NCHUNK, 64, 0, stream>>>(
        bc, dt, xsum, A, wB, cA, cS);
    scan_fixup<<<BATCH * NHEADS, 128, 0, stream>>>(cA, cS, hin);
    scan_pass2<<<BATCH * NHEADS * NCHUNK, 64, 0, stream>>>(
        bc, dt, xsum, A, wB, wC, hin, yredp);

    yfuse_kernel<<<BLTOT * DINNER / 4 / 256, 256, 0, stream>>>(
        x_b, sz, yredp, Dv, y_b);
    gemm_mfma<2048, 0><<<dim3(8, 32), 256, 0, stream>>>(
        y_b, w_out, out, nullptr, nullptr, 1024);
}